// Round 1
// baseline (1287.156 us; speedup 1.0000x reference)
//
#include <hip/hip_runtime.h>
#include <stdint.h>

#define EMB 512
#define THREE_E 1536
#define S_DIM 128
#define L_DIM 128
#define SL 16384
#define NB 2
#define NH 8
#define DH 64
#define K_DIM 512

typedef short bf16x8 __attribute__((ext_vector_type(8)));
typedef float f32x4 __attribute__((ext_vector_type(4)));

__device__ __forceinline__ unsigned short f2bf(float f) {
  unsigned u = __float_as_uint(f);
  u += 0x7fffu + ((u >> 16) & 1u);
  return (unsigned short)(u >> 16);
}
__device__ __forceinline__ float bf2f(unsigned short s) {
  return __uint_as_float((unsigned)s << 16);
}

// ---------------- W fp32 -> bf16 ----------------
__global__ __launch_bounds__(256) void wconv(const float* __restrict__ W,
                                             unsigned short* __restrict__ Wb) {
  int i = blockIdx.x * 256 + threadIdx.x;  // 196608 threads, 4 elems each
  float4 f = ((const float4*)W)[i];
  uint2 o;
  o.x = (unsigned)f2bf(f.x) | ((unsigned)f2bf(f.y) << 16);
  o.y = (unsigned)f2bf(f.z) | ((unsigned)f2bf(f.w) << 16);
  ((uint2*)Wb)[i] = o;
}

// ---------------- x [B,E,S,L] fp32 -> xT [B, S*L, E] bf16 ----------------
__global__ __launch_bounds__(256) void xpose(const float* __restrict__ x,
                                             unsigned short* __restrict__ xT) {
  __shared__ unsigned short t[64][65];
  int b = blockIdx.z;
  int i0 = blockIdx.y * 64;   // channel tile
  int n0 = blockIdx.x * 64;   // spatial tile
  int c = threadIdx.x & 63;
  int r0 = threadIdx.x >> 6;  // 0..3
  const float* xp = x + ((size_t)(b * EMB + i0)) * SL + n0;
  #pragma unroll
  for (int rr = 0; rr < 16; rr++) {
    int r = r0 * 16 + rr;
    t[r][c] = f2bf(xp[(size_t)r * SL + c]);  // coalesced along n
  }
  __syncthreads();
  unsigned short* op = xT + ((size_t)(b * SL + n0)) * EMB + i0;
  #pragma unroll
  for (int rr = 0; rr < 16; rr++) {
    int rn = r0 * 16 + rr;
    op[(size_t)rn * EMB + c] = t[c][rn];     // coalesced along i
  }
}

// ---------------- QKV GEMM: qkv[b][o][n] = W[o][:] . x[b][:][n] (+bias, q*scale), bf16 out ----
__global__ __launch_bounds__(256) void qkv_gemm(const unsigned short* __restrict__ Wb,
                                                const unsigned short* __restrict__ xT,
                                                const float* __restrict__ bias,
                                                unsigned short* __restrict__ qkv) {
  __shared__ unsigned short As[128 * 32];
  __shared__ unsigned short Bs[128 * 32];
  const int tid = threadIdx.x;
  const int b = blockIdx.z;
  const int m0 = blockIdx.y * 128;
  const int n0 = blockIdx.x * 128;
  const int lane = tid & 63;
  const int w = tid >> 6;
  const int wr = (w >> 1) * 64;
  const int wc = (w & 1) * 64;
  const int l15 = lane & 15;
  const int q8 = (lane >> 4) * 8;
  const unsigned short* xb = xT + (size_t)b * SL * EMB;
  f32x4 acc[4][4] = {};
  const int rowA = tid >> 2;           // 0..63
  const int cbA = (tid & 3) << 3;      // bf16 col 0,8,16,24
  for (int k0 = 0; k0 < K_DIM; k0 += 32) {
    __syncthreads();
    *(uint4*)&As[rowA * 32 + cbA]        = *(const uint4*)&Wb[(size_t)(m0 + rowA) * K_DIM + k0 + cbA];
    *(uint4*)&As[(rowA + 64) * 32 + cbA] = *(const uint4*)&Wb[(size_t)(m0 + rowA + 64) * K_DIM + k0 + cbA];
    *(uint4*)&Bs[rowA * 32 + cbA]        = *(const uint4*)&xb[(size_t)(n0 + rowA) * K_DIM + k0 + cbA];
    *(uint4*)&Bs[(rowA + 64) * 32 + cbA] = *(const uint4*)&xb[(size_t)(n0 + rowA + 64) * K_DIM + k0 + cbA];
    __syncthreads();
    bf16x8 av[4], bv[4];
    #pragma unroll
    for (int mt = 0; mt < 4; mt++)
      av[mt] = *(const bf16x8*)&As[(wr + mt * 16 + l15) * 32 + q8];
    #pragma unroll
    for (int nt = 0; nt < 4; nt++)
      bv[nt] = *(const bf16x8*)&Bs[(wc + nt * 16 + l15) * 32 + q8];
    #pragma unroll
    for (int mt = 0; mt < 4; mt++)
      #pragma unroll
      for (int nt = 0; nt < 4; nt++)
        acc[mt][nt] = __builtin_amdgcn_mfma_f32_16x16x32_bf16(av[mt], bv[nt], acc[mt][nt], 0, 0, 0);
  }
  const int q4r = (lane >> 4) * 4;
  #pragma unroll
  for (int mt = 0; mt < 4; mt++) {
    #pragma unroll
    for (int r = 0; r < 4; r++) {
      int row = wr + mt * 16 + q4r + r;
      int o = m0 + row;
      float bo = bias[o];
      float sc = (o < EMB) ? 0.125f : 1.0f;   // Dh^-0.5 folded into q
      size_t obase = ((size_t)b * THREE_E + o) * SL + n0;
      #pragma unroll
      for (int nt = 0; nt < 4; nt++) {
        int col = wc + nt * 16 + l15;
        float v = (acc[mt][nt][r] + bo) * sc;
        qkv[obase + col] = f2bf(v);
      }
    }
  }
}

// ---------------- attention: col_pass=1 attends along S (stride L), else along L (stride 1) ----
__global__ __launch_bounds__(128) void attn(const unsigned short* __restrict__ qkv,
                                            float* __restrict__ out,
                                            int col_pass) {
  __shared__ float Kl[128 * 64];           // 32 KB
  __shared__ unsigned short Vl[128 * 64];  // 16 KB
  const int tid = threadIdx.x;
  const int f = blockIdx.x;
  const int h = blockIdx.y;
  const int b = blockIdx.z;
  const int stride = col_pass ? L_DIM : 1;
  const int fixed = col_pass ? f : f * L_DIM;
  const size_t base = ((size_t)b * THREE_E + h * DH) * SL + fixed;
  const unsigned short* qg = qkv + base;
  const unsigned short* kg = qkv + base + (size_t)EMB * SL;
  const unsigned short* vg = qkv + base + (size_t)(2 * EMB) * SL;
  // stage: thread mapping d-fast (LDS write conflict-free; broadcast reads later)
  #pragma unroll 4
  for (int j = tid; j < 128 * 64; j += 128) {
    int t = j >> 6, d = j & 63;
    size_t g = (size_t)d * SL + (size_t)t * stride;
    Kl[j] = bf2f(kg[g]);
    Vl[j] = vg[g];
  }
  float q[64];
  #pragma unroll
  for (int d = 0; d < 64; d++) q[d] = bf2f(qg[(size_t)d * SL + (size_t)tid * stride]);
  __syncthreads();
  float m = -3.0e38f, lsum = 0.0f;
  float acc[64];
  #pragma unroll
  for (int d = 0; d < 64; d++) acc[d] = 0.0f;
  for (int t = 0; t < 128; t++) {
    const float* kr = &Kl[t * 64];
    float s0 = 0.f, s1 = 0.f, s2 = 0.f, s3 = 0.f;
    #pragma unroll
    for (int d = 0; d < 64; d += 4) {
      s0 = fmaf(q[d],     kr[d],     s0);
      s1 = fmaf(q[d + 1], kr[d + 1], s1);
      s2 = fmaf(q[d + 2], kr[d + 2], s2);
      s3 = fmaf(q[d + 3], kr[d + 3], s3);
    }
    float scv = (s0 + s1) + (s2 + s3);
    if (scv > m) {  // online softmax rescale
      float corr = __builtin_amdgcn_exp2f((m - scv) * 1.44269504088896f);
      lsum *= corr;
      #pragma unroll
      for (int d = 0; d < 64; d++) acc[d] *= corr;
      m = scv;
    }
    float p = __builtin_amdgcn_exp2f((scv - m) * 1.44269504088896f);
    lsum += p;
    const unsigned short* vr = &Vl[t * 64];
    #pragma unroll
    for (int d = 0; d < 64; d += 2) {
      unsigned u = *(const unsigned*)&vr[d];
      acc[d]     = fmaf(p, __uint_as_float(u << 16), acc[d]);
      acc[d + 1] = fmaf(p, __uint_as_float(u & 0xffff0000u), acc[d + 1]);
    }
  }
  float inv = 1.0f / lsum;
  float* og = out + ((size_t)b * EMB + h * DH) * SL + fixed;
  if (col_pass) {
    #pragma unroll
    for (int d = 0; d < 64; d++) og[(size_t)d * SL + (size_t)tid * stride] = acc[d] * inv;
  } else {
    #pragma unroll
    for (int d = 0; d < 64; d++) og[(size_t)d * SL + (size_t)tid * stride] += acc[d] * inv;
  }
}

extern "C" void kernel_launch(void* const* d_in, const int* in_sizes, int n_in,
                              void* d_out, int out_size, void* d_ws, size_t ws_size,
                              hipStream_t stream) {
  const float* x = (const float*)d_in[0];
  const float* W = (const float*)d_in[1];
  const float* bias = (const float*)d_in[2];
  float* out = (float*)d_out;
  // ws layout: qkv bf16 [2][1536][16384] @0 (96MB); xT bf16 [2][16384][512] @96MB (32MB); Wb @128MB (1.5MB)
  unsigned short* qkv = (unsigned short*)d_ws;
  unsigned short* xT = (unsigned short*)((char*)d_ws + 100663296);
  unsigned short* Wb = (unsigned short*)((char*)d_ws + 134217728);

  hipLaunchKernelGGL(wconv, dim3(768), dim3(256), 0, stream, W, Wb);
  hipLaunchKernelGGL(xpose, dim3(256, 8, 2), dim3(256), 0, stream, x, xT);
  hipLaunchKernelGGL(qkv_gemm, dim3(128, 12, 2), dim3(256), 0, stream, Wb, xT, bias, qkv);
  hipLaunchKernelGGL(attn, dim3(128, 8, 2), dim3(128), 0, stream, qkv, out, 1);  // col: writes
  hipLaunchKernelGGL(attn, dim3(128, 8, 2), dim3(128), 0, stream, qkv, out, 0);  // row: accumulates
}

// Round 2
// 297.290 us; speedup vs baseline: 4.3296x; 4.3296x over previous
//
#include <hip/hip_runtime.h>
#include <stdint.h>

#define EMB 512
#define THREE_E 1536
#define SL 16384
#define K_DIM 512

typedef unsigned short ushort;
typedef short bf16x8 __attribute__((ext_vector_type(8)));
typedef float f32x4 __attribute__((ext_vector_type(4)));

__device__ __forceinline__ ushort f2bf(float f) {
  unsigned u = __float_as_uint(f);
  u += 0x7fffu + ((u >> 16) & 1u);
  return (ushort)(u >> 16);
}
__device__ __forceinline__ float bf2f(ushort s) {
  return __uint_as_float((unsigned)s << 16);
}

// ---------------- W fp32 -> bf16 ----------------
__global__ __launch_bounds__(256) void wconv(const float* __restrict__ W,
                                             ushort* __restrict__ Wb) {
  int i = blockIdx.x * 256 + threadIdx.x;
  float4 f = ((const float4*)W)[i];
  uint2 o;
  o.x = (unsigned)f2bf(f.x) | ((unsigned)f2bf(f.y) << 16);
  o.y = (unsigned)f2bf(f.z) | ((unsigned)f2bf(f.w) << 16);
  ((uint2*)Wb)[i] = o;
}

// ---------------- x [B,E,S,L] fp32 -> xT [B, S*L, E] bf16 ----------------
__global__ __launch_bounds__(256) void xpose(const float* __restrict__ x,
                                             ushort* __restrict__ xT) {
  __shared__ ushort t[64][65];
  int b = blockIdx.z;
  int i0 = blockIdx.y * 64;
  int n0 = blockIdx.x * 64;
  int c = threadIdx.x & 63;
  int r0 = threadIdx.x >> 6;
  const float* xp = x + ((size_t)(b * EMB + i0)) * SL + n0;
  #pragma unroll
  for (int rr = 0; rr < 16; rr++) {
    int r = r0 * 16 + rr;
    t[r][c] = f2bf(xp[(size_t)r * SL + c]);
  }
  __syncthreads();
  ushort* op = xT + ((size_t)(b * SL + n0)) * EMB + i0;
  #pragma unroll
  for (int rr = 0; rr < 16; rr++) {
    int rn = r0 * 16 + rr;
    op[(size_t)rn * EMB + c] = t[c][rn];
  }
}

// ---------------- QKV GEMM -> rowQKV [b][sel][h][s][l][d] bf16 ----------------
// m0 tile of 128 = (sel, 2 heads); n0 tile of 128 = one s (all l).
__global__ __launch_bounds__(256) void qkv_gemm(const ushort* __restrict__ Wb,
                                                const ushort* __restrict__ xT,
                                                const float* __restrict__ bias,
                                                ushort* __restrict__ rowQ) {
  __shared__ __align__(16) char sm[34816];  // As(8K)+Bs(8K) main loop; epi[128][136] bf16 epilogue
  ushort* As = (ushort*)sm;
  ushort* Bs = (ushort*)(sm + 8192);
  const int tid = threadIdx.x;
  const int b = blockIdx.z;
  const int m0 = blockIdx.y * 128;
  const int n0 = blockIdx.x * 128;
  const int lane = tid & 63;
  const int w = tid >> 6;
  const int wr = (w >> 1) * 64;
  const int wc = (w & 1) * 64;
  const int l15 = lane & 15;
  const int quad = lane >> 4;
  const int q8 = quad * 8;
  const ushort* xb = xT + (size_t)b * SL * EMB;
  f32x4 acc[4][4] = {};
  const int rowA = tid >> 2;
  const int cbA = (tid & 3) << 3;
  for (int k0 = 0; k0 < K_DIM; k0 += 32) {
    __syncthreads();
    *(uint4*)&As[rowA * 32 + cbA]        = *(const uint4*)&Wb[(size_t)(m0 + rowA) * K_DIM + k0 + cbA];
    *(uint4*)&As[(rowA + 64) * 32 + cbA] = *(const uint4*)&Wb[(size_t)(m0 + rowA + 64) * K_DIM + k0 + cbA];
    *(uint4*)&Bs[rowA * 32 + cbA]        = *(const uint4*)&xb[(size_t)(n0 + rowA) * K_DIM + k0 + cbA];
    *(uint4*)&Bs[(rowA + 64) * 32 + cbA] = *(const uint4*)&xb[(size_t)(n0 + rowA + 64) * K_DIM + k0 + cbA];
    __syncthreads();
    bf16x8 av[4], bv[4];
    #pragma unroll
    for (int mt = 0; mt < 4; mt++)
      av[mt] = *(const bf16x8*)&As[(wr + mt * 16 + l15) * 32 + q8];
    #pragma unroll
    for (int nt = 0; nt < 4; nt++)
      bv[nt] = *(const bf16x8*)&Bs[(wc + nt * 16 + l15) * 32 + q8];
    #pragma unroll
    for (int mt = 0; mt < 4; mt++)
      #pragma unroll
      for (int nt = 0; nt < 4; nt++)
        acc[mt][nt] = __builtin_amdgcn_mfma_f32_16x16x32_bf16(av[mt], bv[nt], acc[mt][nt], 0, 0, 0);
  }
  __syncthreads();  // As/Bs dead; reuse sm as epi
  {
    ushort* epi = (ushort*)sm;  // [l 128][m 136]
    const float sc = (m0 < EMB) ? 0.125f : 1.0f;
    const int q4r = quad * 4;
    #pragma unroll
    for (int mt = 0; mt < 4; mt++) {
      int mb = wr + mt * 16 + q4r;
      float b0 = bias[m0 + mb], b1 = bias[m0 + mb + 1];
      float b2 = bias[m0 + mb + 2], b3 = bias[m0 + mb + 3];
      #pragma unroll
      for (int nt = 0; nt < 4; nt++) {
        int l = wc + nt * 16 + l15;
        unsigned u0 = f2bf((acc[mt][nt][0] + b0) * sc);
        unsigned u1 = f2bf((acc[mt][nt][1] + b1) * sc);
        unsigned u2 = f2bf((acc[mt][nt][2] + b2) * sc);
        unsigned u3 = f2bf((acc[mt][nt][3] + b3) * sc);
        uint2 pk;
        pk.x = u0 | (u1 << 16);
        pk.y = u2 | (u3 << 16);
        *(uint2*)&epi[l * 136 + mb] = pk;
      }
    }
  }
  __syncthreads();
  {
    const ushort* epi = (const ushort*)sm;
    const int sel = m0 >> 9;
    const int hb = (m0 & 511) >> 6;
    const int s = blockIdx.x;
    #pragma unroll
    for (int it = 0; it < 8; it++) {
      int flat = it * 2048 + tid * 8;
      int head = flat >> 13;
      int rem = flat & 8191;
      int l = rem >> 6;
      int dd = rem & 63;
      size_t dst = ((((size_t)(b * 3 + sel) * 8 + hb + head) * 128 + s) * 128 + l) * 64 + dd;
      *(uint4*)&rowQ[dst] = *(const uint4*)&epi[l * 136 + head * 64 + dd];
    }
  }
}

// ---------------- MFMA axial attention ----------------
// colpass=1: block=(l,h,b), queries/keys over s (tstride 8192). Writes tmp [b][h][l][s][d] bf16.
// colpass=0: block=(s,h,b), queries/keys over l (tstride 64). Adds tmp, writes out fp32.
__global__ __launch_bounds__(256) void attn2(const ushort* __restrict__ qkv,
                                             ushort* __restrict__ tmp,
                                             float* __restrict__ out,
                                             int colpass) {
  __shared__ ushort Qs[128 * 72];   // [t][64d pad8]
  __shared__ ushort Ks[128 * 72];
  __shared__ ushort Vt[64 * 136];   // [d][128t pad8]
  __shared__ ushort Ps[64 * 136];   // [s-chunk][128t pad8]
  __shared__ ushort Os[64 * 72];    // [row][64d pad8]
  const int tid = threadIdx.x;
  const int fixed = blockIdx.x;
  const int h = blockIdx.y, b = blockIdx.z;
  const int w = tid >> 6, lane = tid & 63, l15 = lane & 15, quad = lane >> 4;
  const size_t off = colpass ? (size_t)fixed * 64 : (size_t)fixed * 8192;
  const size_t tstr = colpass ? 8192 : 64;
  const ushort* Qg = qkv + ((size_t)(b * 3 + 0) * 8 + h) * 1048576 + off;
  const ushort* Kg = Qg + (size_t)8 * 1048576;
  const ushort* Vg = Qg + (size_t)16 * 1048576;
  ushort* tb = tmp + (size_t)(b * 8 + h) * 1048576;
  // ---- stage Q, K, V(transposed) ----
  {
    int trow = tid >> 3, d0 = (tid & 7) * 8, dg = tid & 7;
    #pragma unroll
    for (int it = 0; it < 4; it++) {
      int t = trow + it * 32;
      size_t g = (size_t)t * tstr + d0;
      *(uint4*)&Qs[t * 72 + d0] = *(const uint4*)&Qg[g];
      *(uint4*)&Ks[t * 72 + d0] = *(const uint4*)&Kg[g];
      uint4 vv = *(const uint4*)&Vg[g];
      ushort* vs = (ushort*)&vv;
      #pragma unroll
      for (int k = 0; k < 8; k++) {  // rotated order: breaks the 8-row mod-32 bank collapse
        int i = (k + dg) & 7;
        Vt[(d0 + i) * 136 + t] = vs[i];
      }
    }
  }
  __syncthreads();
  for (int c = 0; c < 2; c++) {
    if (!colpass) {  // stage col-pass partial into Os
      #pragma unroll
      for (int it = 0; it < 2; it++) {
        int flat = (it * 256 + tid) * 8;
        int row = flat >> 6, dd = flat & 63;
        *(uint4*)&Os[row * 72 + dd] =
            *(const uint4*)&tb[(size_t)(c * 64 + row) * 8192 + (size_t)fixed * 64 + dd];
      }
    }
    const int sb = c * 64 + w * 16;
    bf16x8 aq0 = *(const bf16x8*)&Qs[(sb + l15) * 72 + quad * 8];
    bf16x8 aq1 = *(const bf16x8*)&Qs[(sb + l15) * 72 + 32 + quad * 8];
    f32x4 accS[8];
    #pragma unroll
    for (int nt = 0; nt < 8; nt++) {
      f32x4 z = {0.f, 0.f, 0.f, 0.f};
      bf16x8 bk0 = *(const bf16x8*)&Ks[(nt * 16 + l15) * 72 + quad * 8];
      bf16x8 bk1 = *(const bf16x8*)&Ks[(nt * 16 + l15) * 72 + 32 + quad * 8];
      z = __builtin_amdgcn_mfma_f32_16x16x32_bf16(aq0, bk0, z, 0, 0, 0);
      z = __builtin_amdgcn_mfma_f32_16x16x32_bf16(aq1, bk1, z, 0, 0, 0);
      accS[nt] = z;
    }
    // ---- softmax over t (row-wise; row = quad*4+r, cols across nt & l15 lanes) ----
    float inv[4];
    #pragma unroll
    for (int r = 0; r < 4; r++) {
      float mx = accS[0][r];
      #pragma unroll
      for (int nt = 1; nt < 8; nt++) mx = fmaxf(mx, accS[nt][r]);
      mx = fmaxf(mx, __shfl_xor(mx, 1));
      mx = fmaxf(mx, __shfl_xor(mx, 2));
      mx = fmaxf(mx, __shfl_xor(mx, 4));
      mx = fmaxf(mx, __shfl_xor(mx, 8));
      float s = 0.f;
      #pragma unroll
      for (int nt = 0; nt < 8; nt++) {
        float p = __builtin_amdgcn_exp2f((accS[nt][r] - mx) * 1.44269504088896f);
        accS[nt][r] = p;
        s += p;
      }
      s += __shfl_xor(s, 1);
      s += __shfl_xor(s, 2);
      s += __shfl_xor(s, 4);
      s += __shfl_xor(s, 8);
      inv[r] = 1.0f / s;
    }
    // ---- P -> LDS (wave-private rows) ----
    #pragma unroll
    for (int nt = 0; nt < 8; nt++)
      #pragma unroll
      for (int r = 0; r < 4; r++)
        Ps[(w * 16 + quad * 4 + r) * 136 + nt * 16 + l15] = f2bf(accS[nt][r]);
    __syncthreads();  // also covers Os staging (row pass)
    // ---- O = P @ V ----
    f32x4 accO[4] = {{0.f,0.f,0.f,0.f},{0.f,0.f,0.f,0.f},{0.f,0.f,0.f,0.f},{0.f,0.f,0.f,0.f}};
    #pragma unroll
    for (int kf = 0; kf < 4; kf++) {
      bf16x8 ap = *(const bf16x8*)&Ps[(w * 16 + l15) * 136 + kf * 32 + quad * 8];
      #pragma unroll
      for (int nt = 0; nt < 4; nt++) {
        bf16x8 bv = *(const bf16x8*)&Vt[(nt * 16 + l15) * 136 + kf * 32 + quad * 8];
        accO[nt] = __builtin_amdgcn_mfma_f32_16x16x32_bf16(ap, bv, accO[nt], 0, 0, 0);
      }
    }
    if (colpass) {
      #pragma unroll
      for (int nt = 0; nt < 4; nt++)
        #pragma unroll
        for (int r = 0; r < 4; r++)
          Os[(w * 16 + quad * 4 + r) * 72 + nt * 16 + l15] = f2bf(accO[nt][r] * inv[r]);
      __syncthreads();
      #pragma unroll
      for (int it = 0; it < 2; it++) {
        int flat = (it * 256 + tid) * 8;
        *(uint4*)&tb[(size_t)fixed * 8192 + c * 4096 + flat] =
            *(const uint4*)&Os[(flat >> 6) * 72 + (flat & 63)];
      }
      __syncthreads();
    } else {
      #pragma unroll
      for (int nt = 0; nt < 4; nt++)
        #pragma unroll
        for (int r = 0; r < 4; r++) {
          int row = w * 16 + quad * 4 + r, col = nt * 16 + l15;
          float v = accO[nt][r] * inv[r] + bf2f(Os[row * 72 + col]);
          Os[row * 72 + col] = f2bf(v);
        }
      __syncthreads();
      float* ob = out + (size_t)(b * EMB + h * 64) * SL + (size_t)fixed * 128 + c * 64;
      #pragma unroll
      for (int it = 0; it < 4; it++) {
        int f4 = it * 256 + tid;
        int d = f4 >> 4, l4 = f4 & 15;
        float4 o;
        o.x = bf2f(Os[(l4 * 4 + 0) * 72 + d]);
        o.y = bf2f(Os[(l4 * 4 + 1) * 72 + d]);
        o.z = bf2f(Os[(l4 * 4 + 2) * 72 + d]);
        o.w = bf2f(Os[(l4 * 4 + 3) * 72 + d]);
        *(float4*)&ob[(size_t)d * SL + l4 * 4] = o;
      }
      __syncthreads();
    }
  }
}

extern "C" void kernel_launch(void* const* d_in, const int* in_sizes, int n_in,
                              void* d_out, int out_size, void* d_ws, size_t ws_size,
                              hipStream_t stream) {
  const float* x = (const float*)d_in[0];
  const float* W = (const float*)d_in[1];
  const float* bias = (const float*)d_in[2];
  float* out = (float*)d_out;
  // ws: rowQKV bf16 [b][sel][h][s][l][d] @0 (96MB); xT @96MB (32MB, dead after gemm);
  //     tmp bf16 [b][h][l][s][d] @96MB (32MB, overlays xT); Wb @128MB (1.5MB)
  ushort* rowQ = (ushort*)d_ws;
  ushort* xT = (ushort*)((char*)d_ws + 100663296);
  ushort* tmp = (ushort*)((char*)d_ws + 100663296);
  ushort* Wb = (ushort*)((char*)d_ws + 134217728);

  hipLaunchKernelGGL(wconv, dim3(768), dim3(256), 0, stream, W, Wb);
  hipLaunchKernelGGL(xpose, dim3(256, 8, 2), dim3(256), 0, stream, x, xT);
  hipLaunchKernelGGL(qkv_gemm, dim3(128, 12, 2), dim3(256), 0, stream, Wb, xT, bias, rowQ);
  hipLaunchKernelGGL(attn2, dim3(128, 8, 2), dim3(256), 0, stream, rowQ, tmp, out, 1);
  hipLaunchKernelGGL(attn2, dim3(128, 8, 2), dim3(256), 0, stream, rowQ, tmp, out, 0);
}

// Round 3
// 290.284 us; speedup vs baseline: 4.4341x; 1.0241x over previous
//
#include <hip/hip_runtime.h>
#include <stdint.h>

#define EMB 512
#define THREE_E 1536
#define SL 16384
#define K_DIM 512

typedef unsigned short ushort;
typedef short bf16x8 __attribute__((ext_vector_type(8)));
typedef float f32x4 __attribute__((ext_vector_type(4)));

__device__ __forceinline__ ushort f2bf(float f) {
  unsigned u = __float_as_uint(f);
  u += 0x7fffu + ((u >> 16) & 1u);
  return (ushort)(u >> 16);
}
__device__ __forceinline__ float bf2f(ushort s) {
  return __uint_as_float((unsigned)s << 16);
}

// async global->LDS, 16 B per lane; lds arg must be the wave-uniform base.
__device__ __forceinline__ void async16(const ushort* g, ushort* l) {
  __builtin_amdgcn_global_load_lds(
      (const __attribute__((address_space(1))) unsigned int*)g,
      (__attribute__((address_space(3))) unsigned int*)l, 16, 0, 0);
}

// ---------------- W fp32 -> bf16 ----------------
__global__ __launch_bounds__(256) void wconv(const float* __restrict__ W,
                                             ushort* __restrict__ Wb) {
  int i = blockIdx.x * 256 + threadIdx.x;
  float4 f = ((const float4*)W)[i];
  uint2 o;
  o.x = (unsigned)f2bf(f.x) | ((unsigned)f2bf(f.y) << 16);
  o.y = (unsigned)f2bf(f.z) | ((unsigned)f2bf(f.w) << 16);
  ((uint2*)Wb)[i] = o;
}

// ---------------- x [B,E,S,L] fp32 -> xT [B, S*L, E] bf16 ----------------
__global__ __launch_bounds__(256) void xpose(const float* __restrict__ x,
                                             ushort* __restrict__ xT) {
  __shared__ ushort t[64][65];
  int b = blockIdx.z;
  int i0 = blockIdx.y * 64;
  int n0 = blockIdx.x * 64;
  int c = threadIdx.x & 63;
  int r0 = threadIdx.x >> 6;
  const float* xp = x + ((size_t)(b * EMB + i0)) * SL + n0;
  #pragma unroll
  for (int rr = 0; rr < 16; rr++) {
    int r = r0 * 16 + rr;
    t[r][c] = f2bf(xp[(size_t)r * SL + c]);
  }
  __syncthreads();
  ushort* op = xT + ((size_t)(b * SL + n0)) * EMB + i0;
  #pragma unroll
  for (int rr = 0; rr < 16; rr++) {
    int rn = r0 * 16 + rr;
    op[(size_t)rn * EMB + c] = t[c][rn];
  }
}

// ---------------- QKV GEMM -> rowQKV [b][sel][h][s][l][d] bf16 ----------------
// BK=64, global_load_lds staging, XOR chunk-swizzle (c ^ (row&7)) on 128 B LDS rows.
__global__ __launch_bounds__(256) void qkv_gemm(const ushort* __restrict__ Wb,
                                                const ushort* __restrict__ xT,
                                                const float* __restrict__ bias,
                                                ushort* __restrict__ rowQ) {
  __shared__ __align__(16) char sm[34816];  // As(16K)+Bs(16K) main; epi[128][136] epilogue
  ushort* As = (ushort*)sm;                 // [128][64] swizzled
  ushort* Bs = (ushort*)(sm + 16384);
  const int tid = threadIdx.x;
  const int b = blockIdx.z;
  const int m0 = blockIdx.y * 128;
  const int n0 = blockIdx.x * 128;
  const int lane = tid & 63;
  const int w = tid >> 6;
  const int wr = (w >> 1) * 64;
  const int wc = (w & 1) * 64;
  const int l15 = lane & 15;
  const int quad = lane >> 4;
  const ushort* xb = xT + (size_t)b * SL * EMB;
  f32x4 acc[4][4] = {};
  const int r8 = lane >> 3;             // row within 8-row segment
  const int cg = (lane & 7) ^ r8;       // swizzled global source chunk (const per lane)
  for (int k0 = 0; k0 < K_DIM; k0 += 64) {
    __syncthreads();
    #pragma unroll
    for (int t = 0; t < 4; t++) {
      int seg = 4 * w + t;
      int row = seg * 8 + r8;
      async16(&Wb[(size_t)(m0 + row) * K_DIM + k0 + cg * 8], &As[seg * 512]);
      async16(&xb[(size_t)(n0 + row) * K_DIM + k0 + cg * 8], &Bs[seg * 512]);
    }
    __syncthreads();
    #pragma unroll
    for (int ks = 0; ks < 2; ks++) {
      bf16x8 av[4], bv[4];
      #pragma unroll
      for (int mt = 0; mt < 4; mt++) {
        int row = wr + mt * 16 + l15;
        av[mt] = *(const bf16x8*)&As[row * 64 + (((ks * 4 + quad) ^ (row & 7)) * 8)];
      }
      #pragma unroll
      for (int nt = 0; nt < 4; nt++) {
        int row = wc + nt * 16 + l15;
        bv[nt] = *(const bf16x8*)&Bs[row * 64 + (((ks * 4 + quad) ^ (row & 7)) * 8)];
      }
      #pragma unroll
      for (int mt = 0; mt < 4; mt++)
        #pragma unroll
        for (int nt = 0; nt < 4; nt++)
          acc[mt][nt] = __builtin_amdgcn_mfma_f32_16x16x32_bf16(av[mt], bv[nt], acc[mt][nt], 0, 0, 0);
    }
  }
  __syncthreads();  // As/Bs dead; reuse sm as epi
  {
    ushort* epi = (ushort*)sm;  // [l 128][m 136]
    const float sc = (m0 < EMB) ? 0.125f : 1.0f;
    const int q4r = quad * 4;
    #pragma unroll
    for (int mt = 0; mt < 4; mt++) {
      int mb = wr + mt * 16 + q4r;
      float b0 = bias[m0 + mb], b1 = bias[m0 + mb + 1];
      float b2 = bias[m0 + mb + 2], b3 = bias[m0 + mb + 3];
      #pragma unroll
      for (int nt = 0; nt < 4; nt++) {
        int l = wc + nt * 16 + l15;
        unsigned u0 = f2bf((acc[mt][nt][0] + b0) * sc);
        unsigned u1 = f2bf((acc[mt][nt][1] + b1) * sc);
        unsigned u2 = f2bf((acc[mt][nt][2] + b2) * sc);
        unsigned u3 = f2bf((acc[mt][nt][3] + b3) * sc);
        uint2 pk;
        pk.x = u0 | (u1 << 16);
        pk.y = u2 | (u3 << 16);
        *(uint2*)&epi[l * 136 + mb] = pk;
      }
    }
  }
  __syncthreads();
  {
    const ushort* epi = (const ushort*)sm;
    const int sel = m0 >> 9;
    const int hb = (m0 & 511) >> 6;
    const int s = blockIdx.x;
    #pragma unroll
    for (int it = 0; it < 8; it++) {
      int flat = it * 2048 + tid * 8;
      int head = flat >> 13;
      int rem = flat & 8191;
      int l = rem >> 6;
      int dd = rem & 63;
      size_t dst = ((((size_t)(b * 3 + sel) * 8 + hb + head) * 128 + s) * 128 + l) * 64 + dd;
      *(uint4*)&rowQ[dst] = *(const uint4*)&epi[l * 136 + head * 64 + dd];
    }
  }
}

// ---------------- MFMA axial attention ----------------
// colpass=1: block=(l,h,b), queries over s. Writes tmp [b][h][l][s][d] bf16.
// colpass=0: block=(s,h,b), queries over l. Adds tmp (reg-prefetched), writes out fp32.
// LDS: Qs+Ks+Vt+(Ps∪Os) = 71.7 KB -> 2 blocks/CU.
__global__ __launch_bounds__(256) void attn2(const ushort* __restrict__ qkv,
                                             ushort* __restrict__ tmp,
                                             float* __restrict__ out,
                                             int colpass) {
  __shared__ ushort Qs[128 * 72];   // [t][64d pad8]
  __shared__ ushort Ks[128 * 72];
  __shared__ ushort Vt[64 * 136];   // [d][128t pad8]
  __shared__ ushort PsU[64 * 136];  // Ps [qchunk][128t pad8]  /  Os [row][64d stride72] overlay
  ushort* Ps = PsU;
  ushort* Os = PsU;
  const int tid = threadIdx.x;
  const int fixed = blockIdx.x;
  const int h = blockIdx.y, b = blockIdx.z;
  const int w = tid >> 6, lane = tid & 63, l15 = lane & 15, quad = lane >> 4;
  const size_t off = colpass ? (size_t)fixed * 64 : (size_t)fixed * 8192;
  const size_t tstr = colpass ? 8192 : 64;
  const ushort* Qg = qkv + ((size_t)(b * 3 + 0) * 8 + h) * 1048576 + off;
  const ushort* Kg = Qg + (size_t)8 * 1048576;
  const ushort* Vg = Qg + (size_t)16 * 1048576;
  ushort* tb = tmp + (size_t)(b * 8 + h) * 1048576;
  // ---- stage Q, K, V(transposed, rotated scatter: conflict-free) ----
  {
    int trow = tid >> 3, d0 = (tid & 7) * 8, dg = tid & 7;
    #pragma unroll
    for (int it = 0; it < 4; it++) {
      int t = trow + it * 32;
      size_t g = (size_t)t * tstr + d0;
      *(uint4*)&Qs[t * 72 + d0] = *(const uint4*)&Qg[g];
      *(uint4*)&Ks[t * 72 + d0] = *(const uint4*)&Kg[g];
      uint4 vv = *(const uint4*)&Vg[g];
      ushort* vs = (ushort*)&vv;
      #pragma unroll
      for (int k = 0; k < 8; k++) {
        int i = (k + dg) & 7;
        Vt[(d0 + i) * 136 + t] = vs[i];
      }
    }
  }
  __syncthreads();
  const int row0 = w * 16 + quad * 4;
  for (int c = 0; c < 2; c++) {
    // row pass: prefetch col-pass partial into registers (hidden behind QK+softmax+PV)
    ushort treg[16];
    if (!colpass) {
      const ushort* tp = tb + (size_t)(c * 64 + row0) * 8192 + (size_t)fixed * 64 + l15;
      #pragma unroll
      for (int r = 0; r < 4; r++)
        #pragma unroll
        for (int nt = 0; nt < 4; nt++)
          treg[r * 4 + nt] = tp[(size_t)r * 8192 + nt * 16];
    }
    const int sb = c * 64 + w * 16;
    bf16x8 aq0 = *(const bf16x8*)&Qs[(sb + l15) * 72 + quad * 8];
    bf16x8 aq1 = *(const bf16x8*)&Qs[(sb + l15) * 72 + 32 + quad * 8];
    f32x4 accS[8];
    #pragma unroll
    for (int nt = 0; nt < 8; nt++) {
      f32x4 z = {0.f, 0.f, 0.f, 0.f};
      bf16x8 bk0 = *(const bf16x8*)&Ks[(nt * 16 + l15) * 72 + quad * 8];
      bf16x8 bk1 = *(const bf16x8*)&Ks[(nt * 16 + l15) * 72 + 32 + quad * 8];
      z = __builtin_amdgcn_mfma_f32_16x16x32_bf16(aq0, bk0, z, 0, 0, 0);
      z = __builtin_amdgcn_mfma_f32_16x16x32_bf16(aq1, bk1, z, 0, 0, 0);
      accS[nt] = z;
    }
    // ---- softmax over t ----
    float inv[4];
    #pragma unroll
    for (int r = 0; r < 4; r++) {
      float mx = accS[0][r];
      #pragma unroll
      for (int nt = 1; nt < 8; nt++) mx = fmaxf(mx, accS[nt][r]);
      mx = fmaxf(mx, __shfl_xor(mx, 1));
      mx = fmaxf(mx, __shfl_xor(mx, 2));
      mx = fmaxf(mx, __shfl_xor(mx, 4));
      mx = fmaxf(mx, __shfl_xor(mx, 8));
      float s = 0.f;
      #pragma unroll
      for (int nt = 0; nt < 8; nt++) {
        float p = __builtin_amdgcn_exp2f((accS[nt][r] - mx) * 1.44269504088896f);
        accS[nt][r] = p;
        s += p;
      }
      s += __shfl_xor(s, 1);
      s += __shfl_xor(s, 2);
      s += __shfl_xor(s, 4);
      s += __shfl_xor(s, 8);
      inv[r] = 1.0f / s;
    }
    // ---- P -> LDS ----
    #pragma unroll
    for (int nt = 0; nt < 8; nt++)
      #pragma unroll
      for (int r = 0; r < 4; r++)
        Ps[(row0 + r) * 136 + nt * 16 + l15] = f2bf(accS[nt][r]);
    __syncthreads();
    // ---- O = P @ V ----
    f32x4 accO[4] = {{0.f,0.f,0.f,0.f},{0.f,0.f,0.f,0.f},{0.f,0.f,0.f,0.f},{0.f,0.f,0.f,0.f}};
    #pragma unroll
    for (int kf = 0; kf < 4; kf++) {
      bf16x8 ap = *(const bf16x8*)&Ps[(w * 16 + l15) * 136 + kf * 32 + quad * 8];
      #pragma unroll
      for (int nt = 0; nt < 4; nt++) {
        bf16x8 bv = *(const bf16x8*)&Vt[(nt * 16 + l15) * 136 + kf * 32 + quad * 8];
        accO[nt] = __builtin_amdgcn_mfma_f32_16x16x32_bf16(ap, bv, accO[nt], 0, 0, 0);
      }
    }
    __syncthreads();  // Ps dead -> buffer becomes Os
    #pragma unroll
    for (int nt = 0; nt < 4; nt++)
      #pragma unroll
      for (int r = 0; r < 4; r++) {
        float v = accO[nt][r] * inv[r];
        if (!colpass) v += bf2f(treg[r * 4 + nt]);
        Os[(row0 + r) * 72 + nt * 16 + l15] = f2bf(v);
      }
    __syncthreads();
    if (colpass) {
      #pragma unroll
      for (int it = 0; it < 2; it++) {
        int flat = (it * 256 + tid) * 8;
        *(uint4*)&tb[(size_t)fixed * 8192 + c * 4096 + flat] =
            *(const uint4*)&Os[(flat >> 6) * 72 + (flat & 63)];
      }
    } else {
      float* ob = out + (size_t)(b * EMB + h * 64) * SL + (size_t)fixed * 128 + c * 64;
      #pragma unroll
      for (int it = 0; it < 4; it++) {
        int f4 = it * 256 + tid;
        int d = f4 >> 4, l4 = f4 & 15;
        float4 o;
        o.x = bf2f(Os[(l4 * 4 + 0) * 72 + d]);
        o.y = bf2f(Os[(l4 * 4 + 1) * 72 + d]);
        o.z = bf2f(Os[(l4 * 4 + 2) * 72 + d]);
        o.w = bf2f(Os[(l4 * 4 + 3) * 72 + d]);
        *(float4*)&ob[(size_t)d * SL + l4 * 4] = o;
      }
    }
    __syncthreads();
  }
}

extern "C" void kernel_launch(void* const* d_in, const int* in_sizes, int n_in,
                              void* d_out, int out_size, void* d_ws, size_t ws_size,
                              hipStream_t stream) {
  const float* x = (const float*)d_in[0];
  const float* W = (const float*)d_in[1];
  const float* bias = (const float*)d_in[2];
  float* out = (float*)d_out;
  ushort* rowQ = (ushort*)d_ws;
  ushort* xT = (ushort*)((char*)d_ws + 100663296);
  ushort* tmp = (ushort*)((char*)d_ws + 100663296);
  ushort* Wb = (ushort*)((char*)d_ws + 134217728);

  hipLaunchKernelGGL(wconv, dim3(768), dim3(256), 0, stream, W, Wb);
  hipLaunchKernelGGL(xpose, dim3(256, 8, 2), dim3(256), 0, stream, x, xT);
  hipLaunchKernelGGL(qkv_gemm, dim3(128, 12, 2), dim3(256), 0, stream, Wb, xT, bias, rowQ);
  hipLaunchKernelGGL(attn2, dim3(128, 8, 2), dim3(256), 0, stream, rowQ, tmp, out, 1);
  hipLaunchKernelGGL(attn2, dim3(128, 8, 2), dim3(256), 0, stream, rowQ, tmp, out, 0);
}

// Round 4
// 255.406 us; speedup vs baseline: 5.0396x; 1.1366x over previous
//
#include <hip/hip_runtime.h>
#include <stdint.h>

#define EMB 512
#define THREE_E 1536
#define SL 16384
#define K_DIM 512

typedef unsigned short ushort;
typedef short bf16x8 __attribute__((ext_vector_type(8)));
typedef float f32x4 __attribute__((ext_vector_type(4)));

__device__ __forceinline__ ushort f2bf(float f) {
  unsigned u = __float_as_uint(f);
  u += 0x7fffu + ((u >> 16) & 1u);
  return (ushort)(u >> 16);
}
__device__ __forceinline__ float bf2f(ushort s) {
  return __uint_as_float((unsigned)s << 16);
}

// async global->LDS, 16 B per lane; lds arg must be the wave-uniform base.
__device__ __forceinline__ void async16(const ushort* g, ushort* l) {
  __builtin_amdgcn_global_load_lds(
      (const __attribute__((address_space(1))) unsigned int*)g,
      (__attribute__((address_space(3))) unsigned int*)l, 16, 0, 0);
}

// ---------------- W fp32 -> bf16 ----------------
__global__ __launch_bounds__(256) void wconv(const float* __restrict__ W,
                                             ushort* __restrict__ Wb) {
  int i = blockIdx.x * 256 + threadIdx.x;
  float4 f = ((const float4*)W)[i];
  uint2 o;
  o.x = (unsigned)f2bf(f.x) | ((unsigned)f2bf(f.y) << 16);
  o.y = (unsigned)f2bf(f.z) | ((unsigned)f2bf(f.w) << 16);
  ((uint2*)Wb)[i] = o;
}

// ---------------- x [B,E,S,L] fp32 -> xT [B, S*L, E] bf16 ----------------
__global__ __launch_bounds__(256) void xpose(const float* __restrict__ x,
                                             ushort* __restrict__ xT) {
  __shared__ ushort t[64][65];
  int b = blockIdx.z;
  int i0 = blockIdx.y * 64;
  int n0 = blockIdx.x * 64;
  int c = threadIdx.x & 63;
  int r0 = threadIdx.x >> 6;
  const float* xp = x + ((size_t)(b * EMB + i0)) * SL + n0;
  #pragma unroll
  for (int rr = 0; rr < 16; rr++) {
    int r = r0 * 16 + rr;
    t[r][c] = f2bf(xp[(size_t)r * SL + c]);
  }
  __syncthreads();
  ushort* op = xT + ((size_t)(b * SL + n0)) * EMB + i0;
  #pragma unroll
  for (int rr = 0; rr < 16; rr++) {
    int rn = r0 * 16 + rr;
    op[(size_t)rn * EMB + c] = t[c][rn];
  }
}

// ---------------- QKV GEMM -> rowQKV [b][sel][h][s][l][d] bf16 ----------------
__global__ __launch_bounds__(256) void qkv_gemm(const ushort* __restrict__ Wb,
                                                const ushort* __restrict__ xT,
                                                const float* __restrict__ bias,
                                                ushort* __restrict__ rowQ) {
  __shared__ __align__(16) char sm[34816];
  ushort* As = (ushort*)sm;
  ushort* Bs = (ushort*)(sm + 16384);
  const int tid = threadIdx.x;
  const int b = blockIdx.z;
  const int m0 = blockIdx.y * 128;
  const int n0 = blockIdx.x * 128;
  const int lane = tid & 63;
  const int w = tid >> 6;
  const int wr = (w >> 1) * 64;
  const int wc = (w & 1) * 64;
  const int l15 = lane & 15;
  const int quad = lane >> 4;
  const ushort* xb = xT + (size_t)b * SL * EMB;
  f32x4 acc[4][4] = {};
  const int r8 = lane >> 3;
  const int cg = (lane & 7) ^ r8;
  for (int k0 = 0; k0 < K_DIM; k0 += 64) {
    __syncthreads();
    #pragma unroll
    for (int t = 0; t < 4; t++) {
      int seg = 4 * w + t;
      int row = seg * 8 + r8;
      async16(&Wb[(size_t)(m0 + row) * K_DIM + k0 + cg * 8], &As[seg * 512]);
      async16(&xb[(size_t)(n0 + row) * K_DIM + k0 + cg * 8], &Bs[seg * 512]);
    }
    __syncthreads();
    #pragma unroll
    for (int ks = 0; ks < 2; ks++) {
      bf16x8 av[4], bv[4];
      #pragma unroll
      for (int mt = 0; mt < 4; mt++) {
        int row = wr + mt * 16 + l15;
        av[mt] = *(const bf16x8*)&As[row * 64 + (((ks * 4 + quad) ^ (row & 7)) * 8)];
      }
      #pragma unroll
      for (int nt = 0; nt < 4; nt++) {
        int row = wc + nt * 16 + l15;
        bv[nt] = *(const bf16x8*)&Bs[row * 64 + (((ks * 4 + quad) ^ (row & 7)) * 8)];
      }
      #pragma unroll
      for (int mt = 0; mt < 4; mt++)
        #pragma unroll
        for (int nt = 0; nt < 4; nt++)
          acc[mt][nt] = __builtin_amdgcn_mfma_f32_16x16x32_bf16(av[mt], bv[nt], acc[mt][nt], 0, 0, 0);
    }
  }
  __syncthreads();
  {
    ushort* epi = (ushort*)sm;
    const float sc = (m0 < EMB) ? 0.125f : 1.0f;
    const int q4r = quad * 4;
    #pragma unroll
    for (int mt = 0; mt < 4; mt++) {
      int mb = wr + mt * 16 + q4r;
      float b0 = bias[m0 + mb], b1 = bias[m0 + mb + 1];
      float b2 = bias[m0 + mb + 2], b3 = bias[m0 + mb + 3];
      #pragma unroll
      for (int nt = 0; nt < 4; nt++) {
        int l = wc + nt * 16 + l15;
        unsigned u0 = f2bf((acc[mt][nt][0] + b0) * sc);
        unsigned u1 = f2bf((acc[mt][nt][1] + b1) * sc);
        unsigned u2 = f2bf((acc[mt][nt][2] + b2) * sc);
        unsigned u3 = f2bf((acc[mt][nt][3] + b3) * sc);
        uint2 pk;
        pk.x = u0 | (u1 << 16);
        pk.y = u2 | (u3 << 16);
        *(uint2*)&epi[l * 136 + mb] = pk;
      }
    }
  }
  __syncthreads();
  {
    const ushort* epi = (const ushort*)sm;
    const int sel = m0 >> 9;
    const int hb = (m0 & 511) >> 6;
    const int s = blockIdx.x;
    #pragma unroll
    for (int it = 0; it < 8; it++) {
      int flat = it * 2048 + tid * 8;
      int head = flat >> 13;
      int rem = flat & 8191;
      int l = rem >> 6;
      int dd = rem & 63;
      size_t dst = ((((size_t)(b * 3 + sel) * 8 + hb + head) * 128 + s) * 128 + l) * 64 + dd;
      *(uint4*)&rowQ[dst] = *(const uint4*)&epi[l * 136 + head * 64 + dd];
    }
  }
}

// ---------------- barrier-light MFMA axial attention ----------------
// COL=1: block=(l,h,b), queries over s. Writes tmp [b][h][l][s][d] bf16.
// COL=0: block=(s,h,b), queries over l. Adds tmp, writes out fp32 (O^T via swapped MFMA operands).
// LDS: Ks 16K (async, xor-swizzled) + Vt 17K + Ps 17K = 50 KB -> 3 blocks/CU. ONE __syncthreads.
template <int COL>
__global__ __launch_bounds__(256) void attn3(const ushort* __restrict__ qkv,
                                             ushort* __restrict__ tmp,
                                             float* __restrict__ out) {
  __shared__ ushort Ks[128 * 64];   // [t][64d], chunk-xor-swizzled
  __shared__ ushort Vt[64 * 136];   // [d][128t pad8]
  __shared__ ushort Ps[64 * 136];   // [q][128t pad8], wave-private rows
  const int tid = threadIdx.x;
  const int fixed = blockIdx.x;
  const int h = blockIdx.y, b = blockIdx.z;
  const int w = tid >> 6, lane = tid & 63, l15 = lane & 15, quad = lane >> 4;
  const size_t off = COL ? (size_t)fixed * 64 : (size_t)fixed * 8192;
  const size_t tstr = COL ? 8192 : 64;
  const ushort* Qg = qkv + ((size_t)(b * 3 + 0) * 8 + h) * 1048576 + off;
  const ushort* Kg = Qg + (size_t)8 * 1048576;
  const ushort* Vg = Qg + (size_t)16 * 1048576;
  ushort* tb = tmp + (size_t)(b * 8 + h) * 1048576;
  // ---- K: async global->LDS, xor chunk swizzle ----
  {
    int r8k = lane >> 3;
    int cgk = (lane & 7) ^ r8k;
    #pragma unroll
    for (int t = 0; t < 4; t++) {
      int seg = 4 * w + t;
      int row = seg * 8 + r8k;
      async16(&Kg[(size_t)row * tstr + cgk * 8], &Ks[seg * 512]);
    }
  }
  // ---- V: manual transposed stage (rotated scatter, conflict-free) ----
  {
    int trow = tid >> 3, d0 = (tid & 7) * 8, dg = tid & 7;
    #pragma unroll
    for (int it = 0; it < 4; it++) {
      int t = trow + it * 32;
      uint4 vv = *(const uint4*)&Vg[(size_t)t * tstr + d0];
      ushort* vs = (ushort*)&vv;
      #pragma unroll
      for (int k = 0; k < 8; k++) {
        int i = (k + dg) & 7;
        Vt[(d0 + i) * 136 + t] = vs[i];
      }
    }
  }
  // ---- Q fragments (wave-private): direct global->reg, both chunks ----
  bf16x8 aq[2][2];
  #pragma unroll
  for (int c = 0; c < 2; c++) {
    const ushort* qp = Qg + (size_t)(c * 64 + w * 16 + l15) * tstr + quad * 8;
    aq[c][0] = *(const bf16x8*)qp;
    aq[c][1] = *(const bf16x8*)(qp + 32);
  }
  // ---- row pass: prefetch col-pass partials (lane q = w*16+l15, d = mt*16+quad*4..+3) ----
  uint2 treg[2][4];
  if (!COL) {
    #pragma unroll
    for (int c = 0; c < 2; c++) {
      const ushort* tp = tb + (size_t)(c * 64 + w * 16 + l15) * 8192 + (size_t)fixed * 64 + quad * 4;
      #pragma unroll
      for (int mt = 0; mt < 4; mt++) treg[c][mt] = *(const uint2*)(tp + mt * 16);
    }
  }
  __syncthreads();  // the ONLY block barrier
  const int rx = l15 & 7;
  #pragma unroll
  for (int c = 0; c < 2; c++) {
    // ---- S = Q K^T ----
    f32x4 accS[8];
    #pragma unroll
    for (int nt = 0; nt < 8; nt++) {
      int row = nt * 16 + l15;
      bf16x8 bk0 = *(const bf16x8*)&Ks[row * 64 + ((quad ^ rx) * 8)];
      bf16x8 bk1 = *(const bf16x8*)&Ks[row * 64 + (((quad + 4) ^ rx) * 8)];
      f32x4 z = {0.f, 0.f, 0.f, 0.f};
      z = __builtin_amdgcn_mfma_f32_16x16x32_bf16(aq[c][0], bk0, z, 0, 0, 0);
      z = __builtin_amdgcn_mfma_f32_16x16x32_bf16(aq[c][1], bk1, z, 0, 0, 0);
      accS[nt] = z;
    }
    // ---- softmax over t; fold 1/l into P ----
    float inv[4];
    #pragma unroll
    for (int r = 0; r < 4; r++) {
      float mx = accS[0][r];
      #pragma unroll
      for (int nt = 1; nt < 8; nt++) mx = fmaxf(mx, accS[nt][r]);
      mx = fmaxf(mx, __shfl_xor(mx, 1));
      mx = fmaxf(mx, __shfl_xor(mx, 2));
      mx = fmaxf(mx, __shfl_xor(mx, 4));
      mx = fmaxf(mx, __shfl_xor(mx, 8));
      float s = 0.f;
      #pragma unroll
      for (int nt = 0; nt < 8; nt++) {
        float p = __builtin_amdgcn_exp2f((accS[nt][r] - mx) * 1.44269504088896f);
        accS[nt][r] = p;
        s += p;
      }
      s += __shfl_xor(s, 1);
      s += __shfl_xor(s, 2);
      s += __shfl_xor(s, 4);
      s += __shfl_xor(s, 8);
      inv[r] = 1.0f / s;
    }
    // ---- P -> LDS (wave-private rows; wave-level ordering only) ----
    asm volatile("s_waitcnt lgkmcnt(0)" ::: "memory");  // prior chunk's Ps reads retired
    #pragma unroll
    for (int nt = 0; nt < 8; nt++)
      #pragma unroll
      for (int r = 0; r < 4; r++)
        Ps[(w * 16 + quad * 4 + r) * 136 + nt * 16 + l15] = f2bf(accS[nt][r] * inv[r]);
    asm volatile("s_waitcnt lgkmcnt(0)" ::: "memory");  // Ps writes visible to own wave
    // ---- O = P V  (COL: C[q][d])   or   O^T = V^T P^T  (ROW: C[d][q]) ----
    f32x4 accO[4] = {{0.f,0.f,0.f,0.f},{0.f,0.f,0.f,0.f},{0.f,0.f,0.f,0.f},{0.f,0.f,0.f,0.f}};
    #pragma unroll
    for (int kf = 0; kf < 4; kf++) {
      bf16x8 p = *(const bf16x8*)&Ps[(w * 16 + l15) * 136 + kf * 32 + quad * 8];
      #pragma unroll
      for (int t4 = 0; t4 < 4; t4++) {
        bf16x8 v = *(const bf16x8*)&Vt[(t4 * 16 + l15) * 136 + kf * 32 + quad * 8];
        accO[t4] = COL ? __builtin_amdgcn_mfma_f32_16x16x32_bf16(p, v, accO[t4], 0, 0, 0)
                       : __builtin_amdgcn_mfma_f32_16x16x32_bf16(v, p, accO[t4], 0, 0, 0);
      }
    }
    if (COL) {
      // lane holds (q = w*16+quad*4+r, d = t4*16+l15): 32 B-coalesced bf16 runs
      ushort* tp = tb + (size_t)fixed * 8192 + c * 4096;
      #pragma unroll
      for (int t4 = 0; t4 < 4; t4++)
        #pragma unroll
        for (int r = 0; r < 4; r++)
          tp[(w * 16 + quad * 4 + r) * 64 + t4 * 16 + l15] = f2bf(accO[t4][r]);
    } else {
      // lane holds (d = t4*16+quad*4+r, q = w*16+l15): 64 B-coalesced fp32 runs
      float* ob = out + (size_t)(b * EMB + h * 64) * SL + (size_t)fixed * 128 + c * 64 + w * 16 + l15;
      #pragma unroll
      for (int t4 = 0; t4 < 4; t4++) {
        const ushort* tr = (const ushort*)&treg[c][t4];
        #pragma unroll
        for (int r = 0; r < 4; r++)
          ob[(size_t)(t4 * 16 + quad * 4 + r) * SL] = accO[t4][r] + bf2f(tr[r]);
      }
    }
  }
}

extern "C" void kernel_launch(void* const* d_in, const int* in_sizes, int n_in,
                              void* d_out, int out_size, void* d_ws, size_t ws_size,
                              hipStream_t stream) {
  const float* x = (const float*)d_in[0];
  const float* W = (const float*)d_in[1];
  const float* bias = (const float*)d_in[2];
  float* out = (float*)d_out;
  ushort* rowQ = (ushort*)d_ws;
  ushort* xT = (ushort*)((char*)d_ws + 100663296);
  ushort* tmp = (ushort*)((char*)d_ws + 100663296);
  ushort* Wb = (ushort*)((char*)d_ws + 134217728);

  hipLaunchKernelGGL(wconv, dim3(768), dim3(256), 0, stream, W, Wb);
  hipLaunchKernelGGL(xpose, dim3(256, 8, 2), dim3(256), 0, stream, x, xT);
  hipLaunchKernelGGL(qkv_gemm, dim3(128, 12, 2), dim3(256), 0, stream, Wb, xT, bias, rowQ);
  hipLaunchKernelGGL(attn3<1>, dim3(128, 8, 2), dim3(256), 0, stream, rowQ, tmp, out);
  hipLaunchKernelGGL(attn3<0>, dim3(128, 8, 2), dim3(256), 0, stream, rowQ, tmp, out);
}